// Round 5
// baseline (145.786 us; speedup 1.0000x reference)
//
#include <hip/hip_runtime.h>
#include <math.h>

#define TPB   256
#define PER   8
#define CHUNK 2048      // TPB * PER
#define NCH   512       // TLEN / CHUNK
#define TLEN  1048576
#define K1OFF 31        // 65047 / 2048
#define LOFF  1559      // 65047 % 2048
#define NEMA  4         // 0: short/pred, 1: short/targ, 2: long/pred, 3: long/targ
#define CPL   8         // chunks per lane in pass 2 (NCH/64)

// integer power by repeated squaring, deterministic
__device__ __forceinline__ float ipowf(float base, int e) {
    float r = 1.0f, p = base;
    while (e) { if (e & 1) r *= p; p *= p; e >>= 1; }
    return r;
}

// Transposed LDS layout (CHUNK=2048, t=8j+e): conflict-free for the shifted
// writes (t&7 constant, t>>3 consecutive in j) and aligned reads (e*256+j).
__device__ __forceinline__ int waddr(int t) { return (t & 7) * 256 + (t >> 3); }

__device__ __forceinline__ void load8(const float* __restrict__ p, float v[PER]) {
    const float4* p4 = (const float4*)(p + (size_t)threadIdx.x * PER);
    #pragma unroll
    for (int q = 0; q < PER / 4; ++q) {
        float4 t = p4[q];
        v[q*4+0] = t.x; v[q*4+1] = t.y; v[q*4+2] = t.z; v[q*4+3] = t.w;
    }
}

// Pass 1: per-chunk UNSCALED EMA aggregates: total = sum_j b_j * A8^(255-j).
__global__ __launch_bounds__(TPB) void ldr_partials(
    const float* __restrict__ pred, const float* __restrict__ targ,
    float amS, float amL, float A8S, float A8L,
    float* __restrict__ pB, int rows)
{
    __shared__ float red[4][NEMA];
    const int k = blockIdx.x, r = blockIdx.y, j = threadIdx.x;
    const int lane = j & 63, w = j >> 6;
    const size_t base = (size_t)r * TLEN + (size_t)k * CHUNK;
    float xp[PER], xt[PER];
    load8(pred + base, xp);
    load8(targ + base, xt);
    const float wgtS = ipowf(A8S, 255 - j);
    const float wgtL = ipowf(A8L, 255 - j);
    float v[NEMA];
    #define SEG(E, XV, AM, WG) {                                              \
        float b = 0.0f;                                                       \
        _Pragma("unroll")                                                     \
        for (int e = 0; e < PER; ++e) b = fmaf(AM, b, XV[e]);                 \
        v[E] = b * WG; }
    SEG(0, xp, amS, wgtS)
    SEG(1, xt, amS, wgtS)
    SEG(2, xp, amL, wgtL)
    SEG(3, xt, amL, wgtL)
    #undef SEG
    #pragma unroll
    for (int E = 0; E < NEMA; ++E) {
        float s = v[E];
        #pragma unroll
        for (int d = 32; d > 0; d >>= 1) s += __shfl_xor(s, d, 64);
        if (lane == 0) red[w][E] = s;
    }
    __syncthreads();
    if (j == 0) {
        #pragma unroll
        for (int E = 0; E < NEMA; ++E) {
            float s = red[0][E] + red[1][E] + red[2][E] + red[3][E];
            pB[((size_t)E * rows + r) * NCH + k] = s;
        }
    }
}

// Pass 2: carry-in per chunk, IN-PLACE over the aggregates (lane reads its 8
// values to registers before writing). Chunk coefficient am^2048; lane
// segment coefficient am^16384.
__global__ __launch_bounds__(64) void ldr_carry(
    float* __restrict__ pB,
    float AcS, float AcS8, float AcL, float AcL8, int rows)
{
    const int g = blockIdx.x;              // e*rows + r
    const int lane = threadIdx.x;
    const bool isShort = g < 2 * rows;
    const float Ac  = isShort ? AcS  : AcL;
    const float AcW = isShort ? AcS8 : AcL8;
    float* Bv = pB + (size_t)g * NCH;
    float b8[CPL];
    float B = 0.0f;
    #pragma unroll
    for (int m = 0; m < CPL; ++m) {
        b8[m] = Bv[lane * CPL + m];
        B = fmaf(Ac, B, b8[m]);
    }
    float incl = B, Ad = AcW;
    #pragma unroll
    for (int d = 1; d < 64; d <<= 1) {
        float pb = __shfl_up(incl, d, 64);
        if (lane >= d) incl = fmaf(Ad, pb, incl);
        Ad *= Ad;
    }
    float excl = __shfl_up(incl, 1, 64);
    if (lane == 0) excl = 0.0f;
    float carry = excl;
    #pragma unroll
    for (int m = 0; m < CPL; ++m) {
        Bv[lane * CPL + m] = carry;
        carry = fmaf(Ac, carry, b8[m]);
    }
}

// Pass 3: fused loss. 6 streams (k1:pred/targ long, k2:pred/targ long,
// k:pred/targ short) scanned in ONE 6-wide shfl chain; 2 barriers total.
// W stores the long ratio lt/lp; u-v = log((sp/st)*(lt/lp)).
__global__ __launch_bounds__(TPB) void ldr_loss(
    const float* __restrict__ pred, const float* __restrict__ targ,
    const float* __restrict__ cin,
    float amS, float amL,
    float A8S, float A512S, float A8L, float A512L,
    double* __restrict__ acc, int rows)
{
    __shared__ float W[CHUNK];
    __shared__ float slots[6][4];
    __shared__ float rsum[4];
    const int k = blockIdx.x, r = blockIdx.y, j = threadIdx.x;
    const int lane = j & 63, w = j >> 6;
    const int k1 = (k + K1OFF) % NCH;
    const int k2 = (k + K1OFF + 1) % NCH;
    const size_t rb = (size_t)r * TLEN;

    float x[6][PER];
    load8(pred + rb + (size_t)k1 * CHUNK, x[0]);
    load8(targ + rb + (size_t)k1 * CHUNK, x[1]);
    load8(pred + rb + (size_t)k2 * CHUNK, x[2]);
    load8(targ + rb + (size_t)k2 * CHUNK, x[3]);
    load8(pred + rb + (size_t)k  * CHUNK, x[4]);
    load8(targ + rb + (size_t)k  * CHUNK, x[5]);
    #define CIN(E, KC) cin[((size_t)(E) * rows + r) * NCH + (KC)]
    float cv[6];
    cv[0] = CIN(2, k1); cv[1] = CIN(3, k1);
    cv[2] = CIN(2, k2); cv[3] = CIN(3, k2);
    cv[4] = CIN(0, k);  cv[5] = CIN(1, k);
    #undef CIN

    // per-thread segment partials (6-way ILP, chains of 8)
    float ip[6];
    #pragma unroll
    for (int s = 0; s < 6; ++s) {
        const float am = (s < 4) ? amL : amS;
        float b = 0.0f;
        #pragma unroll
        for (int e = 0; e < PER; ++e) b = fmaf(am, b, x[s][e]);
        ip[s] = b;
    }
    // single 6-wide wave scan with constant multipliers
    float AdL = A8L, AdS = A8S;
    #pragma unroll
    for (int d = 1; d < 64; d <<= 1) {
        float p[6];
        #pragma unroll
        for (int s = 0; s < 6; ++s) p[s] = __shfl_up(ip[s], d, 64);
        if (lane >= d) {
            ip[0] = fmaf(AdL, p[0], ip[0]);
            ip[1] = fmaf(AdL, p[1], ip[1]);
            ip[2] = fmaf(AdL, p[2], ip[2]);
            ip[3] = fmaf(AdL, p[3], ip[3]);
            ip[4] = fmaf(AdS, p[4], ip[4]);
            ip[5] = fmaf(AdS, p[5], ip[5]);
        }
        AdL *= AdL; AdS *= AdS;
    }
    float ex[6];
    #pragma unroll
    for (int s = 0; s < 6; ++s) {
        ex[s] = __shfl_up(ip[s], 1, 64);
        if (lane == 0) ex[s] = 0.0f;
    }
    if (lane == 63) {
        #pragma unroll
        for (int s = 0; s < 6; ++s) slots[s][w] = ip[s];
    }
    __syncthreads();   // barrier 1: slots ready

    const float pLl = ipowf(A8L, lane), pSl = ipowf(A8S, lane);
    const float aTL = pLl * ipowf(A512L, w), aTS = pSl * ipowf(A512S, w);
    float y0[6];
    #pragma unroll
    for (int s = 0; s < 6; ++s) {
        const float A512 = (s < 4) ? A512L : A512S;
        const float aLn  = (s < 4) ? pLl : pSl;
        const float aTh  = (s < 4) ? aTL : aTS;
        float Wc = 0.0f;
        for (int u = 0; u < w; ++u) Wc = fmaf(Wc, A512, slots[s][u]);
        y0[s] = fmaf(aTh, cv[s], fmaf(aLn, Wc, ex[s]));
    }

    // Phase A: long EMAs of k1 -> W[t] for t = l - LOFF >= 0
    {
        float yp = y0[0], yt = y0[1];
        #pragma unroll
        for (int e = 0; e < PER; ++e) {
            yp = fmaf(amL, yp, x[0][e]);
            yt = fmaf(amL, yt, x[1][e]);
            int t = j * PER + e - LOFF;
            if (t >= 0) W[waddr(t)] = __fdividef(yt, yp);
        }
    }
    // Phase B: long EMAs of k2 -> W[l + CHUNK-LOFF] for l < LOFF
    {
        float yp = y0[2], yt = y0[3];
        #pragma unroll
        for (int e = 0; e < PER; ++e) {
            yp = fmaf(amL, yp, x[2][e]);
            yt = fmaf(amL, yt, x[3][e]);
            int l = j * PER + e;
            if (l < LOFF) W[waddr(l + (CHUNK - LOFF))] = __fdividef(yt, yp);
        }
    }
    __syncthreads();   // barrier 2: W ready

    // Phase C: short EMAs of k + loss
    float lsum = 0.0f;
    {
        float yp = y0[4], yt = y0[5];
        #pragma unroll
        for (int e = 0; e < PER; ++e) {
            yp = fmaf(amS, yp, x[4][e]);
            yt = fmaf(amS, yt, x[5][e]);
            float q = __fdividef(yp, yt) * W[(e << 8) + j];   // waddr(8j+e)
            lsum += fabsf(__logf(q));
        }
    }

    #pragma unroll
    for (int d = 32; d > 0; d >>= 1) lsum += __shfl_xor(lsum, d, 64);
    if (lane == 0) rsum[w] = lsum;
    __syncthreads();
    if (j == 0) atomicAdd(acc, (double)(rsum[0] + rsum[1] + rsum[2] + rsum[3]));
}

__global__ void ldr_finalize(const double* __restrict__ acc,
                             float* __restrict__ out, double inv_n)
{
    out[0] = (float)(acc[0] * inv_n);
}

extern "C" void kernel_launch(void* const* d_in, const int* in_sizes, int n_in,
                              void* d_out, int out_size, void* d_ws, size_t ws_size,
                              hipStream_t stream)
{
    const float* pred = (const float*)d_in[0];
    const float* targ = (const float*)d_in[1];
    const int n = in_sizes[0];
    const int rows = n / TLEN;   // 16

    const double csd = 1.0 - exp(-2200.0 / (50.0 * 44100.0));
    const double cld = 1.0 - exp(-2200.0 / (3000.0 * 44100.0));
    const double amSd = 1.0 - csd, amLd = 1.0 - cld;
    const float amS = (float)amSd, amL = (float)amLd;
    const float A8S   = (float)pow(amSd, 8.0);
    const float A512S = (float)pow(amSd, 512.0);
    const float A8L   = (float)pow(amLd, 8.0);
    const float A512L = (float)pow(amLd, 512.0);
    const float AcS  = (float)pow(amSd, 2048.0);
    const float AcS8 = (float)pow(amSd, 16384.0);
    const float AcL  = (float)pow(amLd, 2048.0);
    const float AcL8 = (float)pow(amLd, 16384.0);

    // ws layout: [0,8): double acc; then pB (NEMA*rows*NCH floats), reused
    // in-place as the carry-in buffer by ldr_carry.
    char* wsb = (char*)d_ws;
    double* acc = (double*)wsb;
    float* pB  = (float*)(wsb + 256);

    hipMemsetAsync(acc, 0, sizeof(double), stream);

    dim3 grid(NCH, rows);
    ldr_partials<<<grid, TPB, 0, stream>>>(pred, targ, amS, amL,
                                           A8S, A8L, pB, rows);
    ldr_carry<<<NEMA * rows, 64, 0, stream>>>(pB, AcS, AcS8, AcL, AcL8, rows);
    ldr_loss<<<grid, TPB, 0, stream>>>(pred, targ, pB, amS, amL,
                                       A8S, A512S, A8L, A512L, acc, rows);

    const double inv_n = 1.0 / ((double)rows * (double)TLEN);
    ldr_finalize<<<1, 1, 0, stream>>>(acc, (float*)d_out, inv_n);
}

// Round 6
// 138.720 us; speedup vs baseline: 1.0509x; 1.0509x over previous
//
#include <hip/hip_runtime.h>
#include <math.h>

#define TPB    256
#define PER    8
#define WCH    512          // wave chunk = 64 lanes * PER
#define NCH    2048         // TLEN / WCH
#define TLEN   1048576
#define K1OFF  127          // 65047 / 512
#define LOFF   23           // 65047 % 512
#define NEMA   4            // 0: short/pred, 1: short/targ, 2: long/pred, 3: long/targ
#define CPL    32           // chunks per lane in pass 2 (NCH/64)

// integer power by repeated squaring, deterministic
__device__ __forceinline__ float ipowf(float base, int e) {
    float r = 1.0f, p = base;
    while (e) { if (e & 1) r *= p; p *= p; e >>= 1; }
    return r;
}

// Transposed layout inside a 512-float wave-private window: conflict-free for
// the shifted writes (t%8 const per e, t/8 consecutive in lane -> 2-way = free)
// and the aligned reads (addr = e*64 + lane).
__device__ __forceinline__ int waddr(int t) { return (t & 7) * 64 + (t >> 3); }

__device__ __forceinline__ void load8(const float* __restrict__ p, int lane,
                                      float v[PER]) {
    const float4* p4 = (const float4*)(p + (size_t)lane * PER);
    float4 a = p4[0], b = p4[1];
    v[0] = a.x; v[1] = a.y; v[2] = a.z; v[3] = a.w;
    v[4] = b.x; v[5] = b.y; v[6] = b.z; v[7] = b.w;
}

// Pass 1: wave-per-chunk UNSCALED EMA aggregates (no barriers, no LDS).
// total = sum_lane b_lane * A8^(63-lane).
__global__ __launch_bounds__(TPB, 8) void ldr_partials(
    const float* __restrict__ pred, const float* __restrict__ targ,
    float amS, float amL, float A8S, float A8L,
    float* __restrict__ pB, int rows)
{
    const int j = threadIdx.x, lane = j & 63, w = j >> 6;
    const int k = blockIdx.x * 4 + w, r = blockIdx.y;
    const size_t base = (size_t)r * TLEN + (size_t)k * WCH;
    float xp[PER], xt[PER];
    load8(pred + base, lane, xp);
    load8(targ + base, lane, xt);
    const float wgtS = ipowf(A8S, 63 - lane);
    const float wgtL = ipowf(A8L, 63 - lane);
    float v[NEMA];
    #define SEG(E, XV, AM, WG) {                                              \
        float b = 0.0f;                                                       \
        _Pragma("unroll")                                                     \
        for (int e = 0; e < PER; ++e) b = fmaf(AM, b, XV[e]);                 \
        v[E] = b * WG; }
    SEG(0, xp, amS, wgtS)
    SEG(1, xt, amS, wgtS)
    SEG(2, xp, amL, wgtL)
    SEG(3, xt, amL, wgtL)
    #undef SEG
    #pragma unroll
    for (int E = 0; E < NEMA; ++E) {
        #pragma unroll
        for (int d = 32; d > 0; d >>= 1) v[E] += __shfl_xor(v[E], d, 64);
    }
    if (lane == 0) {
        #pragma unroll
        for (int E = 0; E < NEMA; ++E)
            pB[((size_t)E * rows + r) * NCH + k] = v[E];
    }
}

// Pass 2: carry-in per chunk, IN-PLACE over the aggregates. Chunk coefficient
// Ac = am^512; lane segment coefficient AcW = am^16384.
__global__ __launch_bounds__(64) void ldr_carry(
    float* __restrict__ pB,
    float AcS, float AcSW, float AcL, float AcLW, int rows)
{
    const int g = blockIdx.x;              // e*rows + r
    const int lane = threadIdx.x;
    const bool isShort = g < 2 * rows;
    const float Ac  = isShort ? AcS  : AcL;
    const float AcW = isShort ? AcSW : AcLW;
    float* Bv = pB + (size_t)g * NCH;
    float bm[CPL];
    float B = 0.0f;
    #pragma unroll
    for (int m = 0; m < CPL; ++m) {
        bm[m] = Bv[lane * CPL + m];
        B = fmaf(Ac, B, bm[m]);
    }
    float incl = B, Ad = AcW;
    #pragma unroll
    for (int d = 1; d < 64; d <<= 1) {
        float pb = __shfl_up(incl, d, 64);
        if (lane >= d) incl = fmaf(Ad, pb, incl);
        Ad *= Ad;
    }
    float carry = __shfl_up(incl, 1, 64);
    if (lane == 0) carry = 0.0f;
    #pragma unroll
    for (int m = 0; m < CPL; ++m) {
        Bv[lane * CPL + m] = carry;
        carry = fmaf(Ac, carry, bm[m]);
    }
}

// Pass 3: fused loss, fully wave-autonomous. Each wave owns output chunk k:
// reads 6 streams (long pred/targ of k+127 & k+128, short pred/targ of k),
// one 6-wide in-register wave scan, wave-private shifted window in LDS.
// No __syncthreads until the final 4-wave block reduction.
__global__ __launch_bounds__(TPB, 4) void ldr_loss(
    const float* __restrict__ pred, const float* __restrict__ targ,
    const float* __restrict__ cin,
    float amS, float amL, float A8S, float A8L,
    double* __restrict__ acc, int rows)
{
    __shared__ float W[4][WCH];
    __shared__ float rsum[4];
    const int j = threadIdx.x, lane = j & 63, w = j >> 6;
    const int r = blockIdx.y;
    const int k  = blockIdx.x * 4 + w;
    const int k1 = (k + K1OFF) % NCH;
    const int k2 = (k + K1OFF + 1) % NCH;
    const size_t rb = (size_t)r * TLEN;
    float* Wp = &W[w][0];

    float x[6][PER];
    load8(pred + rb + (size_t)k1 * WCH, lane, x[0]);
    load8(targ + rb + (size_t)k1 * WCH, lane, x[1]);
    load8(pred + rb + (size_t)k2 * WCH, lane, x[2]);
    load8(targ + rb + (size_t)k2 * WCH, lane, x[3]);
    load8(pred + rb + (size_t)k  * WCH, lane, x[4]);
    load8(targ + rb + (size_t)k  * WCH, lane, x[5]);
    #define CIN(E, KC) cin[((size_t)(E) * rows + r) * NCH + (KC)]
    float cv[6];
    cv[0] = CIN(2, k1); cv[1] = CIN(3, k1);
    cv[2] = CIN(2, k2); cv[3] = CIN(3, k2);
    cv[4] = CIN(0, k);  cv[5] = CIN(1, k);
    #undef CIN

    // In-place per-lane prefix EMA (x[s][e] <- EMA starting from 0 at lane
    // start); last element is the lane's segment aggregate.
    #pragma unroll
    for (int s = 0; s < 6; ++s) {
        const float am = (s < 4) ? amL : amS;
        float y = 0.0f;
        #pragma unroll
        for (int e = 0; e < PER; ++e) { y = fmaf(am, y, x[s][e]); x[s][e] = y; }
    }
    // 6-wide wave scan with constant multipliers (depth 6, ILP 6)
    float ip[6];
    #pragma unroll
    for (int s = 0; s < 6; ++s) ip[s] = x[s][PER - 1];
    float AdL = A8L, AdS = A8S;
    #pragma unroll
    for (int d = 1; d < 64; d <<= 1) {
        float p[6];
        #pragma unroll
        for (int s = 0; s < 6; ++s) p[s] = __shfl_up(ip[s], d, 64);
        if (lane >= d) {
            ip[0] = fmaf(AdL, p[0], ip[0]);
            ip[1] = fmaf(AdL, p[1], ip[1]);
            ip[2] = fmaf(AdL, p[2], ip[2]);
            ip[3] = fmaf(AdL, p[3], ip[3]);
            ip[4] = fmaf(AdS, p[4], ip[4]);
            ip[5] = fmaf(AdS, p[5], ip[5]);
        }
        AdL *= AdL; AdS *= AdS;
    }
    // y0[s] = EMA state just before this lane's first element
    const float aTL = ipowf(A8L, lane), aTS = ipowf(A8S, lane);
    float y0[6];
    #pragma unroll
    for (int s = 0; s < 6; ++s) {
        float ex = __shfl_up(ip[s], 1, 64);
        if (lane == 0) ex = 0.0f;
        y0[s] = fmaf((s < 4) ? aTL : aTS, cv[s], ex);
    }

    // Window part A: long EMAs of k1, locals >= LOFF -> t = local - LOFF
    {
        float ap = amL;
        #pragma unroll
        for (int e = 0; e < PER; ++e) {
            int t = lane * PER + e - LOFF;
            if (t >= 0) {
                float yp = fmaf(ap, y0[0], x[0][e]);
                float yt = fmaf(ap, y0[1], x[1][e]);
                Wp[waddr(t)] = __fdividef(yt, yp);
            }
            ap *= amL;
        }
    }
    // Window part B: long EMAs of k2, locals < LOFF -> t = local + WCH-LOFF
    {
        float ap = amL;
        #pragma unroll
        for (int e = 0; e < PER; ++e) {
            int l = lane * PER + e;
            if (l < LOFF) {
                float yp = fmaf(ap, y0[2], x[2][e]);
                float yt = fmaf(ap, y0[3], x[3][e]);
                Wp[waddr(l + (WCH - LOFF))] = __fdividef(yt, yp);
            }
            ap *= amL;
        }
    }
    // Same-wave LDS write->read ordering (cross-lane within the wave).
    asm volatile("s_waitcnt lgkmcnt(0)" ::: "memory");

    // Short EMAs of k + loss: |log( (sp/st) * (lt/lp) )|
    float lsum = 0.0f;
    {
        float ap = amS;
        #pragma unroll
        for (int e = 0; e < PER; ++e) {
            float sp = fmaf(ap, y0[4], x[4][e]);
            float st = fmaf(ap, y0[5], x[5][e]);
            float q = __fdividef(sp, st) * Wp[(e << 6) + lane];  // waddr(8*lane+e)
            lsum += fabsf(__logf(q));
            ap *= amS;
        }
    }
    #pragma unroll
    for (int d = 32; d > 0; d >>= 1) lsum += __shfl_xor(lsum, d, 64);
    if (lane == 0) rsum[w] = lsum;
    __syncthreads();
    if (j == 0) atomicAdd(acc, (double)(rsum[0] + rsum[1] + rsum[2] + rsum[3]));
}

__global__ void ldr_finalize(const double* __restrict__ acc,
                             float* __restrict__ out, double inv_n)
{
    out[0] = (float)(acc[0] * inv_n);
}

extern "C" void kernel_launch(void* const* d_in, const int* in_sizes, int n_in,
                              void* d_out, int out_size, void* d_ws, size_t ws_size,
                              hipStream_t stream)
{
    const float* pred = (const float*)d_in[0];
    const float* targ = (const float*)d_in[1];
    const int n = in_sizes[0];
    const int rows = n / TLEN;   // 16

    const double csd = 1.0 - exp(-2200.0 / (50.0 * 44100.0));
    const double cld = 1.0 - exp(-2200.0 / (3000.0 * 44100.0));
    const double amSd = 1.0 - csd, amLd = 1.0 - cld;
    const float amS = (float)amSd, amL = (float)amLd;
    const float A8S  = (float)pow(amSd, 8.0);
    const float A8L  = (float)pow(amLd, 8.0);
    const float AcS  = (float)pow(amSd, 512.0);
    const float AcSW = (float)pow(amSd, 16384.0);
    const float AcL  = (float)pow(amLd, 512.0);
    const float AcLW = (float)pow(amLd, 16384.0);

    // ws layout: [0,8): double acc; [256,...): pB (NEMA*rows*NCH floats,
    // 512 KB), overwritten in-place with carry-ins by ldr_carry.
    char* wsb = (char*)d_ws;
    double* acc = (double*)wsb;
    float* pB  = (float*)(wsb + 256);

    hipMemsetAsync(acc, 0, sizeof(double), stream);

    dim3 grid(NCH / 4, rows);
    ldr_partials<<<grid, TPB, 0, stream>>>(pred, targ, amS, amL,
                                           A8S, A8L, pB, rows);
    ldr_carry<<<NEMA * rows, 64, 0, stream>>>(pB, AcS, AcSW, AcL, AcLW, rows);
    ldr_loss<<<grid, TPB, 0, stream>>>(pred, targ, pB, amS, amL,
                                       A8S, A8L, acc, rows);

    const double inv_n = 1.0 / ((double)rows * (double)TLEN);
    ldr_finalize<<<1, 1, 0, stream>>>(acc, (float*)d_out, inv_n);
}